// Round 2
// baseline (383.880 us; speedup 1.0000x reference)
//
#include <hip/hip_runtime.h>
#include <hip/hip_bf16.h>
#include <stdint.h>

// LSTM cell, fp32 I/O (per reference), GEMM via bf16 MFMA (threshold is ~1e-1).
//   gates[b, 4H] = [x|h] @ W_stacked^T + b ; per-element LSTM combine, fp32 out.
// B=8192, I=H=1024, C=2048.
//
// Block tile: 128 M x 128 "N" with gate-interleaved N-rows:
//   local n -> gate = (n>>4)&3, column = n0 + ((n>>6)<<4) + (n&15)
// so each wave's 4x4 MFMA tile grid has j-tile == gate: the LSTM combine is
// fully per-lane in registers.
//
// Path A (ws >= 50.3MB): convert x,h,W to bf16 in d_ws once, then m97-style
//   GEMM with global_load_lds width=16.
// Path B (fallback): fused kernel, fp32 float4 loads + in-register cvt + ds_write.

typedef __bf16 bf16x8 __attribute__((ext_vector_type(8)));
typedef float f32x4 __attribute__((ext_vector_type(4)));

#define B_DIM 8192
#define H_DIM 1024
#define C_DIM 2048
#define BM 128
#define BNC 32               // output columns (per gate) per block
#define BK 32
#define K_ITERS (C_DIM / BK) // 64

#define XH_ELEMS (B_DIM * H_DIM)             // 8388608
#define W_ELEMS  (H_DIM * C_DIM)             // 2097152
#define CVT_TOTAL (2 * XH_ELEMS + 4 * W_ELEMS) // 25165824 floats
#define WS_NEEDED ((size_t)CVT_TOTAL * 2)      // 50331648 bytes of bf16

__device__ __forceinline__ void async_cp16(void* lds_dst, const void* g_src) {
    __builtin_amdgcn_global_load_lds(
        (const __attribute__((address_space(1))) void*)g_src,
        (__attribute__((address_space(3))) void*)lds_dst,
        16, 0, 0);
}

// ---------------- fp32 -> bf16 bulk convert (Path A, pass 1) ----------------
__global__ __launch_bounds__(256)
void cvt_kernel(const float* __restrict__ x, const float* __restrict__ h,
                const float* __restrict__ wi, const float* __restrict__ wf,
                const float* __restrict__ wo, const float* __restrict__ wg,
                __hip_bfloat16* __restrict__ dst)
{
    const size_t t = (size_t)blockIdx.x * 256 + threadIdx.x;
    const size_t base = t * 8;
    const float* src;
    size_t off;
    if (base < (size_t)XH_ELEMS)            { src = x; off = base; }
    else if (base < (size_t)2 * XH_ELEMS)   { src = h; off = base - XH_ELEMS; }
    else {
        const size_t wb = base - (size_t)2 * XH_ELEMS;
        const int g = (int)(wb >> 21);          // W_ELEMS = 2^21
        off = wb & (W_ELEMS - 1);
        src = (g == 0) ? wi : (g == 1) ? wf : (g == 2) ? wo : wg;
    }
    const float4 v0 = *(const float4*)(src + off);
    const float4 v1 = *(const float4*)(src + off + 4);
    __hip_bfloat16 tmp[8];
    tmp[0] = __float2bfloat16(v0.x); tmp[1] = __float2bfloat16(v0.y);
    tmp[2] = __float2bfloat16(v0.z); tmp[3] = __float2bfloat16(v0.w);
    tmp[4] = __float2bfloat16(v1.x); tmp[5] = __float2bfloat16(v1.y);
    tmp[6] = __float2bfloat16(v1.z); tmp[7] = __float2bfloat16(v1.w);
    *(bf16x8*)(dst + base) = *(const bf16x8*)tmp;
}

// ---------------- shared epilogue ----------------
__device__ __forceinline__ void lstm_epilogue(
    f32x4 acc[4][4], int m_base, int wr, int quad, int col,
    const float* __restrict__ c,
    const float* __restrict__ pbi, const float* __restrict__ pbf,
    const float* __restrict__ pbo, const float* __restrict__ pbg,
    float* __restrict__ out)
{
    const float vbi = pbi[col];
    const float vbf = pbf[col];
    const float vbo = pbo[col];
    const float vbg = pbg[col];
    const size_t HB = (size_t)B_DIM * H_DIM;
#pragma unroll
    for (int i = 0; i < 4; ++i) {
        const int mb = m_base + wr * 64 + i * 16 + quad * 4;
#pragma unroll
        for (int r = 0; r < 4; ++r) {
            const size_t m = (size_t)(mb + r);
            const float ip = acc[i][0][r] + vbi;
            const float fp = acc[i][1][r] + vbf;
            const float op = acc[i][2][r] + vbo;
            const float gp = acc[i][3][r] + vbg;
            const float ig = 1.f / (1.f + __expf(-ip));
            const float fg = 1.f / (1.f + __expf(-fp));
            const float og = 1.f / (1.f + __expf(-op));
            const float eg = __expf(-2.f * fabsf(gp));
            const float gg = copysignf((1.f - eg) / (1.f + eg), gp);
            const float cin = c[m * H_DIM + col];
            const float ct = fg * cin + ig * gg;
            const float ec = __expf(-2.f * fabsf(ct));
            const float tc = copysignf((1.f - ec) / (1.f + ec), ct);
            out[m * H_DIM + col]      = og * tc;
            out[HB + m * H_DIM + col] = ct;
        }
    }
}

// ---------------- Path A: bf16-staged GEMM (global_load_lds) ----------------
__global__ __launch_bounds__(256, 2)
void lstm_gemm_bf16(const __hip_bfloat16* __restrict__ xb,
                    const __hip_bfloat16* __restrict__ hb,
                    const __hip_bfloat16* __restrict__ Wb,   // [4][H][C]
                    const float* __restrict__ c,
                    const float* __restrict__ pbi, const float* __restrict__ pbf,
                    const float* __restrict__ pbo, const float* __restrict__ pbg,
                    float* __restrict__ out)
{
    __shared__ __hip_bfloat16 As[BM][BK];
    __shared__ __hip_bfloat16 Bs[BM][BK];

    const int tid  = threadIdx.x;
    const int lane = tid & 63;
    const int wave = tid >> 6;
    const int wr   = wave >> 1;
    const int wc   = wave & 1;
    const int quad = lane >> 4;
    const int l16  = lane & 15;

    const int m_base = blockIdx.y * BM;
    const int n0     = blockIdx.x * BNC;

    const __hip_bfloat16* aSrc[2][2];
    char* aDst[2];
#pragma unroll
    for (int a = 0; a < 2; ++a) {
        const int li  = a * 256 + tid;
        const int row = li >> 2;
        const int ch8 = (li & 3) * 8;
        aSrc[a][0] = xb + (size_t)(m_base + row) * H_DIM + ch8;
        aSrc[a][1] = hb + (size_t)(m_base + row) * H_DIM + ch8;
        aDst[a]    = (char*)(&As[0][0]) + (size_t)li * 16;
    }
    const __hip_bfloat16* bSrc[2];
    char* bDst[2];
#pragma unroll
    for (int a = 0; a < 2; ++a) {
        const int li   = a * 256 + tid;
        const int row  = li >> 2;
        const int ch8  = (li & 3) * 8;
        const int gate = (row >> 4) & 3;
        const int grow = n0 + ((row >> 6) << 4) + (row & 15);
        bSrc[a] = Wb + (size_t)gate * W_ELEMS + (size_t)grow * C_DIM + ch8;
        bDst[a] = (char*)(&Bs[0][0]) + (size_t)li * 16;
    }

    int aRow[4], bRow[4];
#pragma unroll
    for (int i = 0; i < 4; ++i) aRow[i] = wr * 64 + i * 16 + l16;
#pragma unroll
    for (int j = 0; j < 4; ++j) bRow[j] = wc * 64 + j * 16 + l16;
    const int kOff = quad * 8;

    f32x4 acc[4][4];
#pragma unroll
    for (int i = 0; i < 4; ++i)
#pragma unroll
        for (int j = 0; j < 4; ++j)
            acc[i][j] = (f32x4){0.f, 0.f, 0.f, 0.f};

    for (int kt = 0; kt < K_ITERS; ++kt) {
        const int hsel = (kt >= (H_DIM / BK));
        const int koff = (kt & 31) * BK;
#pragma unroll
        for (int a = 0; a < 2; ++a)
            async_cp16(aDst[a], aSrc[a][hsel] + koff);
#pragma unroll
        for (int a = 0; a < 2; ++a)
            async_cp16(bDst[a], bSrc[a] + kt * BK);
        __syncthreads();

        bf16x8 av[4], bv[4];
#pragma unroll
        for (int i = 0; i < 4; ++i)
            av[i] = *(const bf16x8*)&As[aRow[i]][kOff];
#pragma unroll
        for (int j = 0; j < 4; ++j)
            bv[j] = *(const bf16x8*)&Bs[bRow[j]][kOff];
#pragma unroll
        for (int i = 0; i < 4; ++i)
#pragma unroll
            for (int j = 0; j < 4; ++j)
                acc[i][j] = __builtin_amdgcn_mfma_f32_16x16x32_bf16(
                    av[i], bv[j], acc[i][j], 0, 0, 0);
        __syncthreads();
    }

    lstm_epilogue(acc, m_base, wr, quad, n0 + wc * 16 + l16,
                  c, pbi, pbf, pbo, pbg, out);
}

// ---------------- Path B: fused fp32-load + in-register cvt ----------------
__global__ __launch_bounds__(256, 2)
void lstm_gemm_fused(const float* __restrict__ x, const float* __restrict__ h,
                     const float* __restrict__ Wi, const float* __restrict__ Wf,
                     const float* __restrict__ Wo, const float* __restrict__ Wg,
                     const float* __restrict__ c,
                     const float* __restrict__ pbi, const float* __restrict__ pbf,
                     const float* __restrict__ pbo, const float* __restrict__ pbg,
                     float* __restrict__ out)
{
    __shared__ __hip_bfloat16 As[BM][BK];
    __shared__ __hip_bfloat16 Bs[BM][BK];

    const int tid  = threadIdx.x;
    const int lane = tid & 63;
    const int wave = tid >> 6;
    const int wr   = wave >> 1;
    const int wc   = wave & 1;
    const int quad = lane >> 4;
    const int l16  = lane & 15;

    const int m_base = blockIdx.y * BM;
    const int n0     = blockIdx.x * BNC;

    // staging: thread -> (row = tid>>1, colh = (tid&1)*16), 16 fp32 -> 16 bf16
    const int srow = tid >> 1;
    const int scol = (tid & 1) * 16;
    const float* aS[2] = {
        x + (size_t)(m_base + srow) * H_DIM + scol,
        h + (size_t)(m_base + srow) * H_DIM + scol
    };
    const int gate = (srow >> 4) & 3;
    const int grow = n0 + ((srow >> 6) << 4) + (srow & 15);
    const float* Wsel = (gate == 0) ? Wi : (gate == 1) ? Wf : (gate == 2) ? Wo : Wg;
    const float* bS = Wsel + (size_t)grow * C_DIM + scol;

    int aRow[4], bRow[4];
#pragma unroll
    for (int i = 0; i < 4; ++i) aRow[i] = wr * 64 + i * 16 + l16;
#pragma unroll
    for (int j = 0; j < 4; ++j) bRow[j] = wc * 64 + j * 16 + l16;
    const int kOff = quad * 8;

    f32x4 acc[4][4];
#pragma unroll
    for (int i = 0; i < 4; ++i)
#pragma unroll
        for (int j = 0; j < 4; ++j)
            acc[i][j] = (f32x4){0.f, 0.f, 0.f, 0.f};

    for (int kt = 0; kt < K_ITERS; ++kt) {
        const int hsel = (kt >= (H_DIM / BK));
        const int koff = (kt & 31) * BK;

        const float* ap = aS[hsel] + koff;
        const float* bp = bS + kt * BK;
        float4 a0 = *(const float4*)(ap);
        float4 a1 = *(const float4*)(ap + 4);
        float4 a2 = *(const float4*)(ap + 8);
        float4 a3 = *(const float4*)(ap + 12);
        float4 b0 = *(const float4*)(bp);
        float4 b1 = *(const float4*)(bp + 4);
        float4 b2 = *(const float4*)(bp + 8);
        float4 b3 = *(const float4*)(bp + 12);

        __hip_bfloat16 ta[16], tb[16];
        ta[0]=__float2bfloat16(a0.x);  ta[1]=__float2bfloat16(a0.y);
        ta[2]=__float2bfloat16(a0.z);  ta[3]=__float2bfloat16(a0.w);
        ta[4]=__float2bfloat16(a1.x);  ta[5]=__float2bfloat16(a1.y);
        ta[6]=__float2bfloat16(a1.z);  ta[7]=__float2bfloat16(a1.w);
        ta[8]=__float2bfloat16(a2.x);  ta[9]=__float2bfloat16(a2.y);
        ta[10]=__float2bfloat16(a2.z); ta[11]=__float2bfloat16(a2.w);
        ta[12]=__float2bfloat16(a3.x); ta[13]=__float2bfloat16(a3.y);
        ta[14]=__float2bfloat16(a3.z); ta[15]=__float2bfloat16(a3.w);
        tb[0]=__float2bfloat16(b0.x);  tb[1]=__float2bfloat16(b0.y);
        tb[2]=__float2bfloat16(b0.z);  tb[3]=__float2bfloat16(b0.w);
        tb[4]=__float2bfloat16(b1.x);  tb[5]=__float2bfloat16(b1.y);
        tb[6]=__float2bfloat16(b1.z);  tb[7]=__float2bfloat16(b1.w);
        tb[8]=__float2bfloat16(b2.x);  tb[9]=__float2bfloat16(b2.y);
        tb[10]=__float2bfloat16(b2.z); tb[11]=__float2bfloat16(b2.w);
        tb[12]=__float2bfloat16(b3.x); tb[13]=__float2bfloat16(b3.y);
        tb[14]=__float2bfloat16(b3.z); tb[15]=__float2bfloat16(b3.w);

        *(bf16x8*)&As[srow][scol]     = *(const bf16x8*)&ta[0];
        *(bf16x8*)&As[srow][scol + 8] = *(const bf16x8*)&ta[8];
        *(bf16x8*)&Bs[srow][scol]     = *(const bf16x8*)&tb[0];
        *(bf16x8*)&Bs[srow][scol + 8] = *(const bf16x8*)&tb[8];
        __syncthreads();

        bf16x8 av[4], bv[4];
#pragma unroll
        for (int i = 0; i < 4; ++i)
            av[i] = *(const bf16x8*)&As[aRow[i]][kOff];
#pragma unroll
        for (int j = 0; j < 4; ++j)
            bv[j] = *(const bf16x8*)&Bs[bRow[j]][kOff];
#pragma unroll
        for (int i = 0; i < 4; ++i)
#pragma unroll
            for (int j = 0; j < 4; ++j)
                acc[i][j] = __builtin_amdgcn_mfma_f32_16x16x32_bf16(
                    av[i], bv[j], acc[i][j], 0, 0, 0);
        __syncthreads();
    }

    lstm_epilogue(acc, m_base, wr, quad, n0 + wc * 16 + l16,
                  c, pbi, pbf, pbo, pbg, out);
}

extern "C" void kernel_launch(void* const* d_in, const int* in_sizes, int n_in,
                              void* d_out, int out_size, void* d_ws, size_t ws_size,
                              hipStream_t stream) {
    const float* x  = (const float*)d_in[0];
    const float* h  = (const float*)d_in[1];
    const float* c  = (const float*)d_in[2];
    const float* Wi = (const float*)d_in[3];
    const float* Wf = (const float*)d_in[4];
    const float* Wo = (const float*)d_in[5];
    const float* Wg = (const float*)d_in[6];
    const float* bi = (const float*)d_in[7];
    const float* bfp= (const float*)d_in[8];
    const float* bo = (const float*)d_in[9];
    const float* bg = (const float*)d_in[10];
    float* out = (float*)d_out;

    dim3 grid(H_DIM / BNC, B_DIM / BM);  // (32, 64) = 2048 blocks

    if (ws_size >= WS_NEEDED) {
        __hip_bfloat16* wsb = (__hip_bfloat16*)d_ws;
        cvt_kernel<<<CVT_TOTAL / 8 / 256, 256, 0, stream>>>(x, h, Wi, Wf, Wo, Wg, wsb);
        lstm_gemm_bf16<<<grid, dim3(256), 0, stream>>>(
            wsb, wsb + XH_ELEMS, wsb + 2 * (size_t)XH_ELEMS,
            c, bi, bfp, bo, bg, out);
    } else {
        lstm_gemm_fused<<<grid, dim3(256), 0, stream>>>(
            x, h, Wi, Wf, Wo, Wg, c, bi, bfp, bo, bg, out);
    }
}

// Round 4
// 322.404 us; speedup vs baseline: 1.1907x; 1.1907x over previous
//
#include <hip/hip_runtime.h>
#include <hip/hip_bf16.h>
#include <stdint.h>

// LSTM cell, fp32 I/O, GEMM via bf16 MFMA.
//   gates[b, 4H] = [x|h] @ W_stacked^T + b ; per-element LSTM combine, fp32 out.
// B=8192, I=H=1024, C=2048.
//
// Round 3 = round 2 design with the nontemporal builtin applied to clang
// ext_vector types (HIP float4 is a class -> rejected by the builtin).
// Design: BK=64 (32 MFMA per barrier drain) + XOR chunk swizzle so the
// ds_read_b128 fragment reads are bank-conflict-free; swizzle permutes the
// SOURCE addresses because global_load_lds forces lane-linear LDS dst.

typedef __bf16 bf16x8 __attribute__((ext_vector_type(8)));
typedef float f32x4 __attribute__((ext_vector_type(4)));   // clang vector: ok for nontemporal

#define B_DIM 8192
#define H_DIM 1024
#define C_DIM 2048
#define BM 128
#define BNC 32               // output columns (per gate) per block
#define BK 64
#define K_ITERS (C_DIM / BK) // 32

#define XH_ELEMS (B_DIM * H_DIM)               // 8388608
#define W_ELEMS  (H_DIM * C_DIM)               // 2097152
#define CVT_TOTAL (2 * XH_ELEMS + 4 * W_ELEMS) // 25165824 floats
#define WS_NEEDED ((size_t)CVT_TOTAL * 2)      // 50331648 bytes of bf16

__device__ __forceinline__ void async_cp16(void* lds_dst, const void* g_src) {
    __builtin_amdgcn_global_load_lds(
        (const __attribute__((address_space(1))) void*)g_src,
        (__attribute__((address_space(3))) void*)lds_dst,
        16, 0, 0);
}

// ---------------- fp32 -> bf16 bulk convert (pass 1) ----------------
__global__ __launch_bounds__(256)
void cvt_kernel(const float* __restrict__ x, const float* __restrict__ h,
                const float* __restrict__ wi, const float* __restrict__ wf,
                const float* __restrict__ wo, const float* __restrict__ wg,
                __hip_bfloat16* __restrict__ dst)
{
    const size_t t = (size_t)blockIdx.x * 256 + threadIdx.x;
    const size_t base = t * 16;
    const float* src;
    size_t off;
    if (base < (size_t)XH_ELEMS)            { src = x; off = base; }
    else if (base < (size_t)2 * XH_ELEMS)   { src = h; off = base - XH_ELEMS; }
    else {
        const size_t wb = base - (size_t)2 * XH_ELEMS;
        const int g = (int)(wb >> 21);          // W_ELEMS = 2^21
        off = wb & (W_ELEMS - 1);
        src = (g == 0) ? wi : (g == 1) ? wf : (g == 2) ? wo : wg;
    }
    f32x4 v[4];
#pragma unroll
    for (int q = 0; q < 4; ++q)
        v[q] = __builtin_nontemporal_load((const f32x4*)(src + off + q * 4));
    __hip_bfloat16 tmp[16];
#pragma unroll
    for (int q = 0; q < 4; ++q) {
        tmp[q*4+0] = __float2bfloat16(v[q][0]);
        tmp[q*4+1] = __float2bfloat16(v[q][1]);
        tmp[q*4+2] = __float2bfloat16(v[q][2]);
        tmp[q*4+3] = __float2bfloat16(v[q][3]);
    }
    __builtin_nontemporal_store(*(const bf16x8*)&tmp[0], (bf16x8*)(dst + base));
    __builtin_nontemporal_store(*(const bf16x8*)&tmp[8], (bf16x8*)(dst + base + 8));
}

// ---------------- GEMM + LSTM epilogue ----------------
__global__ __launch_bounds__(256, 2)
void lstm_gemm_bf16(const __hip_bfloat16* __restrict__ xb,
                    const __hip_bfloat16* __restrict__ hb,
                    const __hip_bfloat16* __restrict__ Wb,   // [4][H][C]
                    const float* __restrict__ c,
                    const float* __restrict__ pbi, const float* __restrict__ pbf,
                    const float* __restrict__ pbo, const float* __restrict__ pbg,
                    float* __restrict__ out)
{
    __shared__ __hip_bfloat16 As[BM][BK];   // 16 KB, XOR-swizzled chunks
    __shared__ __hip_bfloat16 Bs[BM][BK];   // 16 KB, gate-interleaved + swizzled

    const int tid  = threadIdx.x;
    const int lane = tid & 63;
    const int wave = tid >> 6;
    const int wr   = wave >> 1;
    const int wc   = wave & 1;
    const int quad = lane >> 4;
    const int l16  = lane & 15;

    const int m_base = blockIdx.y * BM;
    const int n0     = blockIdx.x * BNC;

    // staging: 4 issues x 256 threads x 16B = 16 KB per matrix.
    // li -> row = li>>3, dst chunk = li&7; SOURCE chunk = (li&7) ^ (row&7).
    const __hip_bfloat16* aSrc[4][2];
    const __hip_bfloat16* bSrc[4];
    char *aDst[4], *bDst[4];
#pragma unroll
    for (int a = 0; a < 4; ++a) {
        const int li   = a * 256 + tid;
        const int row  = li >> 3;
        const int sch  = ((li & 7) ^ (row & 7)) * 8;   // source element offset
        aSrc[a][0] = xb + (size_t)(m_base + row) * H_DIM + sch;
        aSrc[a][1] = hb + (size_t)(m_base + row) * H_DIM + sch;
        aDst[a]    = (char*)(&As[0][0]) + (size_t)li * 16;
        const int gate = (row >> 4) & 3;
        const int grow = n0 + ((row >> 6) << 4) + (row & 15);
        bSrc[a] = Wb + (size_t)gate * W_ELEMS + (size_t)grow * C_DIM + sch;
        bDst[a] = (char*)(&Bs[0][0]) + (size_t)li * 16;
    }

    int aRow[4], bRow[4];
#pragma unroll
    for (int i = 0; i < 4; ++i) aRow[i] = wr * 64 + i * 16 + l16;
#pragma unroll
    for (int j = 0; j < 4; ++j) bRow[j] = wc * 64 + j * 16 + l16;

    f32x4 acc[4][4];
#pragma unroll
    for (int i = 0; i < 4; ++i)
#pragma unroll
        for (int j = 0; j < 4; ++j)
            acc[i][j] = (f32x4){0.f, 0.f, 0.f, 0.f};

    for (int kt = 0; kt < K_ITERS; ++kt) {
        const int hsel = (kt >= (H_DIM / BK));   // 0: x-half, 1: h-half
        const int koff = (kt & ((H_DIM / BK) - 1)) * BK;
#pragma unroll
        for (int a = 0; a < 4; ++a)
            async_cp16(aDst[a], aSrc[a][hsel] + koff);
#pragma unroll
        for (int a = 0; a < 4; ++a)
            async_cp16(bDst[a], bSrc[a] + kt * BK);
        __syncthreads();   // drains vmcnt(0)

#pragma unroll
        for (int s = 0; s < 2; ++s) {
            bf16x8 av[4], bv[4];
#pragma unroll
            for (int i = 0; i < 4; ++i) {
                const int r  = aRow[i];
                const int ch = (s * 4 + quad) ^ (r & 7);
                av[i] = *(const bf16x8*)((const char*)&As[0][0] + r * (BK * 2) + ch * 16);
            }
#pragma unroll
            for (int j = 0; j < 4; ++j) {
                const int r  = bRow[j];
                const int ch = (s * 4 + quad) ^ (r & 7);
                bv[j] = *(const bf16x8*)((const char*)&Bs[0][0] + r * (BK * 2) + ch * 16);
            }
#pragma unroll
            for (int i = 0; i < 4; ++i)
#pragma unroll
                for (int j = 0; j < 4; ++j)
                    acc[i][j] = __builtin_amdgcn_mfma_f32_16x16x32_bf16(
                        av[i], bv[j], acc[i][j], 0, 0, 0);
        }
        __syncthreads();
    }

    // ---- epilogue: per-lane LSTM combine (j-tile == gate) ----
    const int col = n0 + wc * 16 + l16;
    const float vbi = pbi[col];
    const float vbf = pbf[col];
    const float vbo = pbo[col];
    const float vbg = pbg[col];
    const size_t HB = (size_t)B_DIM * H_DIM;
#pragma unroll
    for (int i = 0; i < 4; ++i) {
        const int mb = m_base + wr * 64 + i * 16 + quad * 4;
#pragma unroll
        for (int r = 0; r < 4; ++r) {
            const size_t m = (size_t)(mb + r);
            const float ip = acc[i][0][r] + vbi;
            const float fp = acc[i][1][r] + vbf;
            const float op = acc[i][2][r] + vbo;
            const float gp = acc[i][3][r] + vbg;
            const float ig = 1.f / (1.f + __expf(-ip));
            const float fg = 1.f / (1.f + __expf(-fp));
            const float og = 1.f / (1.f + __expf(-op));
            const float eg = __expf(-2.f * fabsf(gp));
            const float gg = copysignf((1.f - eg) / (1.f + eg), gp);
            const float cin = c[m * H_DIM + col];
            const float ct = fg * cin + ig * gg;
            const float ec = __expf(-2.f * fabsf(ct));
            const float tc = copysignf((1.f - ec) / (1.f + ec), ct);
            out[m * H_DIM + col]      = og * tc;
            out[HB + m * H_DIM + col] = ct;
        }
    }
}

// ---------------- fallback: fused fp32-load path (small ws) ----------------
__global__ __launch_bounds__(256, 2)
void lstm_gemm_fused(const float* __restrict__ x, const float* __restrict__ h,
                     const float* __restrict__ Wi, const float* __restrict__ Wf,
                     const float* __restrict__ Wo, const float* __restrict__ Wg,
                     const float* __restrict__ c,
                     const float* __restrict__ pbi, const float* __restrict__ pbf,
                     const float* __restrict__ pbo, const float* __restrict__ pbg,
                     float* __restrict__ out)
{
    __shared__ __hip_bfloat16 As[BM][BK];
    __shared__ __hip_bfloat16 Bs[BM][BK];

    const int tid  = threadIdx.x;
    const int lane = tid & 63;
    const int wave = tid >> 6;
    const int wr   = wave >> 1;
    const int wc   = wave & 1;
    const int quad = lane >> 4;
    const int l16  = lane & 15;

    const int m_base = blockIdx.y * BM;
    const int n0     = blockIdx.x * BNC;

    // staging: thread -> row = tid>>1, 32 cols, col half = (tid&1)*32
    const int srow = tid >> 1;
    const int scol = (tid & 1) * 32;
    const float* aS[2] = {
        x + (size_t)(m_base + srow) * H_DIM + scol,
        h + (size_t)(m_base + srow) * H_DIM + scol
    };
    const int gate = (srow >> 4) & 3;
    const int grow = n0 + ((srow >> 6) << 4) + (srow & 15);
    const float* Wsel = (gate == 0) ? Wi : (gate == 1) ? Wf : (gate == 2) ? Wo : Wg;
    const float* bS = Wsel + (size_t)grow * C_DIM + scol;

    int aRow[4], bRow[4];
#pragma unroll
    for (int i = 0; i < 4; ++i) aRow[i] = wr * 64 + i * 16 + l16;
#pragma unroll
    for (int j = 0; j < 4; ++j) bRow[j] = wc * 64 + j * 16 + l16;

    f32x4 acc[4][4];
#pragma unroll
    for (int i = 0; i < 4; ++i)
#pragma unroll
        for (int j = 0; j < 4; ++j)
            acc[i][j] = (f32x4){0.f, 0.f, 0.f, 0.f};

    for (int kt = 0; kt < K_ITERS; ++kt) {
        const int hsel = (kt >= (H_DIM / BK));
        const int koff = (kt & ((H_DIM / BK) - 1)) * BK;
        const float* ap = aS[hsel] + koff;
        const float* bp = bS + kt * BK;
        __hip_bfloat16 ta[32], tb[32];
#pragma unroll
        for (int q = 0; q < 8; ++q) {
            f32x4 a = *(const f32x4*)(ap + q * 4);
            f32x4 b = *(const f32x4*)(bp + q * 4);
            ta[q*4+0]=__float2bfloat16(a[0]); ta[q*4+1]=__float2bfloat16(a[1]);
            ta[q*4+2]=__float2bfloat16(a[2]); ta[q*4+3]=__float2bfloat16(a[3]);
            tb[q*4+0]=__float2bfloat16(b[0]); tb[q*4+1]=__float2bfloat16(b[1]);
            tb[q*4+2]=__float2bfloat16(b[2]); tb[q*4+3]=__float2bfloat16(b[3]);
        }
        // swizzled LDS write: chunk c of this 32-col half -> slot (c ^ (row&7))
#pragma unroll
        for (int q = 0; q < 4; ++q) {
            const int ch  = (scol / 8) + q;
            const int sl  = ch ^ (srow & 7);
            *(bf16x8*)((char*)&As[0][0] + srow * (BK * 2) + sl * 16) = *(const bf16x8*)&ta[q * 8];
            *(bf16x8*)((char*)&Bs[0][0] + srow * (BK * 2) + sl * 16) = *(const bf16x8*)&tb[q * 8];
        }
        __syncthreads();

#pragma unroll
        for (int s = 0; s < 2; ++s) {
            bf16x8 av[4], bv[4];
#pragma unroll
            for (int i = 0; i < 4; ++i) {
                const int r  = aRow[i];
                const int ch = (s * 4 + quad) ^ (r & 7);
                av[i] = *(const bf16x8*)((const char*)&As[0][0] + r * (BK * 2) + ch * 16);
            }
#pragma unroll
            for (int j = 0; j < 4; ++j) {
                const int r  = bRow[j];
                const int ch = (s * 4 + quad) ^ (r & 7);
                bv[j] = *(const bf16x8*)((const char*)&Bs[0][0] + r * (BK * 2) + ch * 16);
            }
#pragma unroll
            for (int i = 0; i < 4; ++i)
#pragma unroll
                for (int j = 0; j < 4; ++j)
                    acc[i][j] = __builtin_amdgcn_mfma_f32_16x16x32_bf16(
                        av[i], bv[j], acc[i][j], 0, 0, 0);
        }
        __syncthreads();
    }

    const int col = n0 + wc * 16 + l16;
    const float vbi = pbi[col];
    const float vbf = pbf[col];
    const float vbo = pbo[col];
    const float vbg = pbg[col];
    const size_t HB = (size_t)B_DIM * H_DIM;
#pragma unroll
    for (int i = 0; i < 4; ++i) {
        const int mb = m_base + wr * 64 + i * 16 + quad * 4;
#pragma unroll
        for (int r = 0; r < 4; ++r) {
            const size_t m = (size_t)(mb + r);
            const float ip = acc[i][0][r] + vbi;
            const float fp = acc[i][1][r] + vbf;
            const float op = acc[i][2][r] + vbo;
            const float gp = acc[i][3][r] + vbg;
            const float ig = 1.f / (1.f + __expf(-ip));
            const float fg = 1.f / (1.f + __expf(-fp));
            const float og = 1.f / (1.f + __expf(-op));
            const float eg = __expf(-2.f * fabsf(gp));
            const float gg = copysignf((1.f - eg) / (1.f + eg), gp);
            const float cin = c[m * H_DIM + col];
            const float ct = fg * cin + ig * gg;
            const float ec = __expf(-2.f * fabsf(ct));
            const float tc = copysignf((1.f - ec) / (1.f + ec), ct);
            out[m * H_DIM + col]      = og * tc;
            out[HB + m * H_DIM + col] = ct;
        }
    }
}

extern "C" void kernel_launch(void* const* d_in, const int* in_sizes, int n_in,
                              void* d_out, int out_size, void* d_ws, size_t ws_size,
                              hipStream_t stream) {
    const float* x  = (const float*)d_in[0];
    const float* h  = (const float*)d_in[1];
    const float* c  = (const float*)d_in[2];
    const float* Wi = (const float*)d_in[3];
    const float* Wf = (const float*)d_in[4];
    const float* Wo = (const float*)d_in[5];
    const float* Wg = (const float*)d_in[6];
    const float* bi = (const float*)d_in[7];
    const float* bfp= (const float*)d_in[8];
    const float* bo = (const float*)d_in[9];
    const float* bg = (const float*)d_in[10];
    float* out = (float*)d_out;

    dim3 grid(H_DIM / BNC, B_DIM / BM);  // (32, 64) = 2048 blocks

    if (ws_size >= WS_NEEDED) {
        __hip_bfloat16* wsb = (__hip_bfloat16*)d_ws;
        cvt_kernel<<<CVT_TOTAL / 16 / 256, 256, 0, stream>>>(x, h, Wi, Wf, Wo, Wg, wsb);
        lstm_gemm_bf16<<<grid, dim3(256), 0, stream>>>(
            wsb, wsb + XH_ELEMS, wsb + 2 * (size_t)XH_ELEMS,
            c, bi, bfp, bo, bg, out);
    } else {
        lstm_gemm_fused<<<grid, dim3(256), 0, stream>>>(
            x, h, Wi, Wf, Wo, Wg, c, bi, bfp, bo, bg, out);
    }
}

// Round 5
// 302.695 us; speedup vs baseline: 1.2682x; 1.0651x over previous
//
#include <hip/hip_runtime.h>
#include <hip/hip_bf16.h>
#include <stdint.h>

// LSTM cell, fp32 I/O, GEMM via bf16 MFMA.
//   gates[b, 4H] = [x|h] @ W_stacked^T + b ; per-element LSTM combine, fp32 out.
// B=8192, I=H=1024, C=2048.
//
// Round 5:
//  - cvt pass: fully coalesced (one f32x4 per thread, 16B/lane), cached loads
//    (round-4 NT + 64B/lane stride caused ~4x read amplification).
//  - GEMM: __launch_bounds__(256,3) -> 3 blocks/CU (was 2). LDS 32KB*3=96KB
//    fits 160KB; more resident waves overlap the per-block vmcnt(0) barrier
//    drains (the residual stall at MfmaUtil 37%).
//  - Keeps: BK=64, XOR chunk swizzle (bank conflicts measured 0),
//    global_load_lds width=16, gate-interleaved N-rows, in-register epilogue.

typedef __bf16 bf16x8 __attribute__((ext_vector_type(8)));
typedef __bf16 bf16x4 __attribute__((ext_vector_type(4)));
typedef float f32x4 __attribute__((ext_vector_type(4)));

#define B_DIM 8192
#define H_DIM 1024
#define C_DIM 2048
#define BM 128
#define BNC 32               // output columns (per gate) per block
#define BK 64
#define K_ITERS (C_DIM / BK) // 32

#define XH_ELEMS (B_DIM * H_DIM)               // 8388608
#define W_ELEMS  (H_DIM * C_DIM)               // 2097152
#define CVT_TOTAL (2 * XH_ELEMS + 4 * W_ELEMS) // 25165824 floats
#define WS_NEEDED ((size_t)CVT_TOTAL * 2)      // 50331648 bytes of bf16

__device__ __forceinline__ void async_cp16(void* lds_dst, const void* g_src) {
    __builtin_amdgcn_global_load_lds(
        (const __attribute__((address_space(1))) void*)g_src,
        (__attribute__((address_space(3))) void*)lds_dst,
        16, 0, 0);
}

// ---------------- fp32 -> bf16 bulk convert (pass 1), coalesced ----------------
__global__ __launch_bounds__(256)
void cvt_kernel(const float* __restrict__ x, const float* __restrict__ h,
                const float* __restrict__ wi, const float* __restrict__ wf,
                const float* __restrict__ wo, const float* __restrict__ wg,
                __hip_bfloat16* __restrict__ dst)
{
    const size_t t = (size_t)blockIdx.x * 256 + threadIdx.x;
    const size_t base = t * 4;                 // 16B/lane, lane-contiguous
    const float* src;
    size_t off;
    if (base < (size_t)XH_ELEMS)            { src = x; off = base; }
    else if (base < (size_t)2 * XH_ELEMS)   { src = h; off = base - XH_ELEMS; }
    else {
        const size_t wb = base - (size_t)2 * XH_ELEMS;
        const int g = (int)(wb >> 21);          // W_ELEMS = 2^21
        off = wb & (W_ELEMS - 1);
        src = (g == 0) ? wi : (g == 1) ? wf : (g == 2) ? wo : wg;
    }
    const f32x4 v = *(const f32x4*)(src + off);
    __hip_bfloat16 tmp[4];
    tmp[0] = __float2bfloat16(v[0]);
    tmp[1] = __float2bfloat16(v[1]);
    tmp[2] = __float2bfloat16(v[2]);
    tmp[3] = __float2bfloat16(v[3]);
    *(bf16x4*)(dst + base) = *(const bf16x4*)tmp;
}

// ---------------- GEMM + LSTM epilogue ----------------
__global__ __launch_bounds__(256, 3)
void lstm_gemm_bf16(const __hip_bfloat16* __restrict__ xb,
                    const __hip_bfloat16* __restrict__ hb,
                    const __hip_bfloat16* __restrict__ Wb,   // [4][H][C]
                    const float* __restrict__ c,
                    const float* __restrict__ pbi, const float* __restrict__ pbf,
                    const float* __restrict__ pbo, const float* __restrict__ pbg,
                    float* __restrict__ out)
{
    __shared__ __hip_bfloat16 As[BM][BK];   // 16 KB, XOR-swizzled chunks
    __shared__ __hip_bfloat16 Bs[BM][BK];   // 16 KB, gate-interleaved + swizzled

    const int tid  = threadIdx.x;
    const int lane = tid & 63;
    const int wave = tid >> 6;
    const int wr   = wave >> 1;
    const int wc   = wave & 1;
    const int quad = lane >> 4;
    const int l16  = lane & 15;

    const int m_base = blockIdx.y * BM;
    const int n0     = blockIdx.x * BNC;

    // staging: 4 issues x 256 threads x 16B = 16 KB per matrix.
    // li -> row = li>>3, dst chunk = li&7; SOURCE chunk = (li&7) ^ (row&7).
    const __hip_bfloat16* aSrc[4][2];
    const __hip_bfloat16* bSrc[4];
    char *aDst[4], *bDst[4];
#pragma unroll
    for (int a = 0; a < 4; ++a) {
        const int li   = a * 256 + tid;
        const int row  = li >> 3;
        const int sch  = ((li & 7) ^ (row & 7)) * 8;   // source element offset
        aSrc[a][0] = xb + (size_t)(m_base + row) * H_DIM + sch;
        aSrc[a][1] = hb + (size_t)(m_base + row) * H_DIM + sch;
        aDst[a]    = (char*)(&As[0][0]) + (size_t)li * 16;
        const int gate = (row >> 4) & 3;
        const int grow = n0 + ((row >> 6) << 4) + (row & 15);
        bSrc[a] = Wb + (size_t)gate * W_ELEMS + (size_t)grow * C_DIM + sch;
        bDst[a] = (char*)(&Bs[0][0]) + (size_t)li * 16;
    }

    int aRow[4], bRow[4];
#pragma unroll
    for (int i = 0; i < 4; ++i) aRow[i] = wr * 64 + i * 16 + l16;
#pragma unroll
    for (int j = 0; j < 4; ++j) bRow[j] = wc * 64 + j * 16 + l16;

    f32x4 acc[4][4];
#pragma unroll
    for (int i = 0; i < 4; ++i)
#pragma unroll
        for (int j = 0; j < 4; ++j)
            acc[i][j] = (f32x4){0.f, 0.f, 0.f, 0.f};

    for (int kt = 0; kt < K_ITERS; ++kt) {
        const int hsel = (kt >= (H_DIM / BK));   // 0: x-half, 1: h-half
        const int koff = (kt & ((H_DIM / BK) - 1)) * BK;
#pragma unroll
        for (int a = 0; a < 4; ++a)
            async_cp16(aDst[a], aSrc[a][hsel] + koff);
#pragma unroll
        for (int a = 0; a < 4; ++a)
            async_cp16(bDst[a], bSrc[a] + kt * BK);
        __syncthreads();   // drains vmcnt(0)

#pragma unroll
        for (int s = 0; s < 2; ++s) {
            bf16x8 av[4], bv[4];
#pragma unroll
            for (int i = 0; i < 4; ++i) {
                const int r  = aRow[i];
                const int ch = (s * 4 + quad) ^ (r & 7);
                av[i] = *(const bf16x8*)((const char*)&As[0][0] + r * (BK * 2) + ch * 16);
            }
#pragma unroll
            for (int j = 0; j < 4; ++j) {
                const int r  = bRow[j];
                const int ch = (s * 4 + quad) ^ (r & 7);
                bv[j] = *(const bf16x8*)((const char*)&Bs[0][0] + r * (BK * 2) + ch * 16);
            }
#pragma unroll
            for (int i = 0; i < 4; ++i)
#pragma unroll
                for (int j = 0; j < 4; ++j)
                    acc[i][j] = __builtin_amdgcn_mfma_f32_16x16x32_bf16(
                        av[i], bv[j], acc[i][j], 0, 0, 0);
        }
        __syncthreads();
    }

    // ---- epilogue: per-lane LSTM combine (j-tile == gate) ----
    const int col = n0 + wc * 16 + l16;
    const float vbi = pbi[col];
    const float vbf = pbf[col];
    const float vbo = pbo[col];
    const float vbg = pbg[col];
    const size_t HB = (size_t)B_DIM * H_DIM;
#pragma unroll
    for (int i = 0; i < 4; ++i) {
        const int mb = m_base + wr * 64 + i * 16 + quad * 4;
#pragma unroll
        for (int r = 0; r < 4; ++r) {
            const size_t m = (size_t)(mb + r);
            const float ip = acc[i][0][r] + vbi;
            const float fp = acc[i][1][r] + vbf;
            const float op = acc[i][2][r] + vbo;
            const float gp = acc[i][3][r] + vbg;
            const float ig = 1.f / (1.f + __expf(-ip));
            const float fg = 1.f / (1.f + __expf(-fp));
            const float og = 1.f / (1.f + __expf(-op));
            const float eg = __expf(-2.f * fabsf(gp));
            const float gg = copysignf((1.f - eg) / (1.f + eg), gp);
            const float cin = c[m * H_DIM + col];
            const float ct = fg * cin + ig * gg;
            const float ec = __expf(-2.f * fabsf(ct));
            const float tc = copysignf((1.f - ec) / (1.f + ec), ct);
            out[m * H_DIM + col]      = og * tc;
            out[HB + m * H_DIM + col] = ct;
        }
    }
}

// ---------------- fallback: fused fp32-load path (small ws) ----------------
__global__ __launch_bounds__(256, 2)
void lstm_gemm_fused(const float* __restrict__ x, const float* __restrict__ h,
                     const float* __restrict__ Wi, const float* __restrict__ Wf,
                     const float* __restrict__ Wo, const float* __restrict__ Wg,
                     const float* __restrict__ c,
                     const float* __restrict__ pbi, const float* __restrict__ pbf,
                     const float* __restrict__ pbo, const float* __restrict__ pbg,
                     float* __restrict__ out)
{
    __shared__ __hip_bfloat16 As[BM][BK];
    __shared__ __hip_bfloat16 Bs[BM][BK];

    const int tid  = threadIdx.x;
    const int lane = tid & 63;
    const int wave = tid >> 6;
    const int wr   = wave >> 1;
    const int wc   = wave & 1;
    const int quad = lane >> 4;
    const int l16  = lane & 15;

    const int m_base = blockIdx.y * BM;
    const int n0     = blockIdx.x * BNC;

    const int srow = tid >> 1;
    const int scol = (tid & 1) * 32;
    const float* aS[2] = {
        x + (size_t)(m_base + srow) * H_DIM + scol,
        h + (size_t)(m_base + srow) * H_DIM + scol
    };
    const int gate = (srow >> 4) & 3;
    const int grow = n0 + ((srow >> 6) << 4) + (srow & 15);
    const float* Wsel = (gate == 0) ? Wi : (gate == 1) ? Wf : (gate == 2) ? Wo : Wg;
    const float* bS = Wsel + (size_t)grow * C_DIM + scol;

    int aRow[4], bRow[4];
#pragma unroll
    for (int i = 0; i < 4; ++i) aRow[i] = wr * 64 + i * 16 + l16;
#pragma unroll
    for (int j = 0; j < 4; ++j) bRow[j] = wc * 64 + j * 16 + l16;

    f32x4 acc[4][4];
#pragma unroll
    for (int i = 0; i < 4; ++i)
#pragma unroll
        for (int j = 0; j < 4; ++j)
            acc[i][j] = (f32x4){0.f, 0.f, 0.f, 0.f};

    for (int kt = 0; kt < K_ITERS; ++kt) {
        const int hsel = (kt >= (H_DIM / BK));
        const int koff = (kt & ((H_DIM / BK) - 1)) * BK;
        const float* ap = aS[hsel] + koff;
        const float* bp = bS + kt * BK;
        __hip_bfloat16 ta[32], tb[32];
#pragma unroll
        for (int q = 0; q < 8; ++q) {
            f32x4 a = *(const f32x4*)(ap + q * 4);
            f32x4 b = *(const f32x4*)(bp + q * 4);
            ta[q*4+0]=__float2bfloat16(a[0]); ta[q*4+1]=__float2bfloat16(a[1]);
            ta[q*4+2]=__float2bfloat16(a[2]); ta[q*4+3]=__float2bfloat16(a[3]);
            tb[q*4+0]=__float2bfloat16(b[0]); tb[q*4+1]=__float2bfloat16(b[1]);
            tb[q*4+2]=__float2bfloat16(b[2]); tb[q*4+3]=__float2bfloat16(b[3]);
        }
#pragma unroll
        for (int q = 0; q < 4; ++q) {
            const int ch  = (scol / 8) + q;
            const int sl  = ch ^ (srow & 7);
            *(bf16x8*)((char*)&As[0][0] + srow * (BK * 2) + sl * 16) = *(const bf16x8*)&ta[q * 8];
            *(bf16x8*)((char*)&Bs[0][0] + srow * (BK * 2) + sl * 16) = *(const bf16x8*)&tb[q * 8];
        }
        __syncthreads();

#pragma unroll
        for (int s = 0; s < 2; ++s) {
            bf16x8 av[4], bv[4];
#pragma unroll
            for (int i = 0; i < 4; ++i) {
                const int r  = aRow[i];
                const int ch = (s * 4 + quad) ^ (r & 7);
                av[i] = *(const bf16x8*)((const char*)&As[0][0] + r * (BK * 2) + ch * 16);
            }
#pragma unroll
            for (int j = 0; j < 4; ++j) {
                const int r  = bRow[j];
                const int ch = (s * 4 + quad) ^ (r & 7);
                bv[j] = *(const bf16x8*)((const char*)&Bs[0][0] + r * (BK * 2) + ch * 16);
            }
#pragma unroll
            for (int i = 0; i < 4; ++i)
#pragma unroll
                for (int j = 0; j < 4; ++j)
                    acc[i][j] = __builtin_amdgcn_mfma_f32_16x16x32_bf16(
                        av[i], bv[j], acc[i][j], 0, 0, 0);
        }
        __syncthreads();
    }

    const int col = n0 + wc * 16 + l16;
    const float vbi = pbi[col];
    const float vbf = pbf[col];
    const float vbo = pbo[col];
    const float vbg = pbg[col];
    const size_t HB = (size_t)B_DIM * H_DIM;
#pragma unroll
    for (int i = 0; i < 4; ++i) {
        const int mb = m_base + wr * 64 + i * 16 + quad * 4;
#pragma unroll
        for (int r = 0; r < 4; ++r) {
            const size_t m = (size_t)(mb + r);
            const float ip = acc[i][0][r] + vbi;
            const float fp = acc[i][1][r] + vbf;
            const float op = acc[i][2][r] + vbo;
            const float gp = acc[i][3][r] + vbg;
            const float ig = 1.f / (1.f + __expf(-ip));
            const float fg = 1.f / (1.f + __expf(-fp));
            const float og = 1.f / (1.f + __expf(-op));
            const float eg = __expf(-2.f * fabsf(gp));
            const float gg = copysignf((1.f - eg) / (1.f + eg), gp);
            const float cin = c[m * H_DIM + col];
            const float ct = fg * cin + ig * gg;
            const float ec = __expf(-2.f * fabsf(ct));
            const float tc = copysignf((1.f - ec) / (1.f + ec), ct);
            out[m * H_DIM + col]      = og * tc;
            out[HB + m * H_DIM + col] = ct;
        }
    }
}

extern "C" void kernel_launch(void* const* d_in, const int* in_sizes, int n_in,
                              void* d_out, int out_size, void* d_ws, size_t ws_size,
                              hipStream_t stream) {
    const float* x  = (const float*)d_in[0];
    const float* h  = (const float*)d_in[1];
    const float* c  = (const float*)d_in[2];
    const float* Wi = (const float*)d_in[3];
    const float* Wf = (const float*)d_in[4];
    const float* Wo = (const float*)d_in[5];
    const float* Wg = (const float*)d_in[6];
    const float* bi = (const float*)d_in[7];
    const float* bfp= (const float*)d_in[8];
    const float* bo = (const float*)d_in[9];
    const float* bg = (const float*)d_in[10];
    float* out = (float*)d_out;

    dim3 grid(H_DIM / BNC, B_DIM / BM);  // (32, 64) = 2048 blocks

    if (ws_size >= WS_NEEDED) {
        __hip_bfloat16* wsb = (__hip_bfloat16*)d_ws;
        cvt_kernel<<<CVT_TOTAL / 4 / 256, 256, 0, stream>>>(x, h, Wi, Wf, Wo, Wg, wsb);
        lstm_gemm_bf16<<<grid, dim3(256), 0, stream>>>(
            wsb, wsb + XH_ELEMS, wsb + 2 * (size_t)XH_ELEMS,
            c, bi, bfp, bo, bg, out);
    } else {
        lstm_gemm_fused<<<grid, dim3(256), 0, stream>>>(
            x, h, Wi, Wf, Wo, Wg, c, bi, bfp, bo, bg, out);
    }
}